// Round 9
// baseline (337.018 us; speedup 1.0000x reference)
//
#include <hip/hip_runtime.h>
#include <cstdint>
#include <cmath>

#define BDIM 256

constexpr int Bsz = 32;
constexpr int Tt  = 512;
constexpr int Nn  = 1024;
constexpr int SEG = 16;    // T split into 16 segments of 32 for the scan
constexpr int SLEN = 32;
constexpr int SPLITS = 8;  // split-K
constexpr int NKT = (2 * Bsz * Tt / 32) / SPLITS;  // 128 ktiles per split
constexpr float A_PLUS  = 0.005f;
constexpr float A_MINUS = 0.00525f;
constexpr float A_TP    = 0.0001f;
constexpr float A_TM    = 0.0001f;

typedef __attribute__((ext_vector_type(8))) short short8;   // 8 bf16 = 4 VGPRs
typedef __attribute__((ext_vector_type(4))) float float4v;  // MFMA acc / float4

__device__ __forceinline__ unsigned short f2bf(float f) {
  // round-to-nearest-even fp32 -> bf16 (values are finite)
  unsigned u = __float_as_uint(f);
  u += 0x7fffu + ((u >> 16) & 1u);
  return (unsigned short)(u >> 16);
}

// ---------------------------------------------------------------------------
// Phase 1: trace recurrences -> bf16 operands, segment-scan parallelized.
// NEW (R8): each thread owns 4 consecutive n via float4 loads — a wave's
// 16-lane group reads 256 B contiguous per segment (4x denser VMEM), and each
// thread runs 4 independent recurrences (4x ILP). Phase A streams loads
// (endpoints only, low VGPR); Phase B re-reads in batches of 8 (L2-warm) and
// emits 4 operand rows. Scan over 16 segments via LDS (exact: r is linear in
// spikes; carry_i = carry_{i-1}*d^32 + local_{i-1}).
// Operand layout (row = k = b*T + t):
//   Abuf rows [0,Kc)=P (decayed trace factor), rows [Kc,2Kc)=pre
//   Bbuf rows [0,Kc)=post,                     rows [Kc,2Kc)=-Y
// Tile blob = ((row>>5)*8 + (n>>7)); inside: (n&127)*32 + ((j>>3)^((n>>1)&3))*8+(j&7)
// ---------------------------------------------------------------------------
__global__ __launch_bounds__(BDIM) void trace_kernel(
    const float* __restrict__ pre, const float* __restrict__ post,
    unsigned short* __restrict__ Abuf, unsigned short* __restrict__ Bbuf,
    float d_plus, float d_x, float d_minus, float d_y)
{
  // blockIdx.x: [0, 2*32*16): nb(16) | b(32) | side(2)
  int nb   = blockIdx.x & 15;
  int b    = (blockIdx.x >> 4) & 31;
  int side = blockIdx.x >> 9;
  int tid  = threadIdx.x;
  int seg  = tid >> 4;                             // [0,16)
  int nl   = tid & 15;
  int n4   = nb * 64 + nl * 4;                     // 4 consecutive n

  const float* sp = (side ? post : pre) + (size_t)b * Tt * Nn + n4;
  float da = side ? d_minus : d_plus;
  float db = side ? d_y     : d_x;
  float c1 = side ? -A_MINUS : A_PLUS;
  float c2 = side ? -A_TM    : A_TP;
  unsigned short* dbuf = side ? Bbuf : Abuf;
  int t0 = seg * SLEN;
  int Kc = Bsz * Tt;

  // --- Phase A: stream segment spikes, keep only local endpoints ---
  float4v l1 = (float4v){0.f,0.f,0.f,0.f}, l2 = (float4v){0.f,0.f,0.f,0.f};
#pragma unroll
  for (int j = 0; j < SLEN; ++j) {
    float4v s = *(const float4v*)(sp + (size_t)(t0 + j) * Nn);
    l1 = l1 * da + s;                              // combined step: decay then add
    l2 = l2 * db + s;
  }

  // d^32 via 5 squarings
  float dL1 = da, dL2 = db;
#pragma unroll
  for (int q = 0; q < 5; ++q) { dL1 *= dL1; dL2 *= dL2; }

  // --- Exclusive scan over the 16 segments of each chain, via LDS ---
  __shared__ float4v lds1[SEG][16], lds2[SEG][16];   // 8 KB total
  lds1[seg][nl] = l1; lds2[seg][nl] = l2;
  __syncthreads();
  float4v tr1 = (float4v){0.f,0.f,0.f,0.f}, tr2 = (float4v){0.f,0.f,0.f,0.f};
#pragma unroll
  for (int m = 0; m < SEG - 1; ++m) {
    if (m < seg) {
      tr1 = tr1 * dL1 + lds1[m][nl];
      tr2 = tr2 * dL2 + lds2[m][nl];
    }
  }

  // --- Phase B: re-read (L2-warm) in batches of 8, emit operands ---
#pragma unroll
  for (int g2 = 0; g2 < SLEN / 8; ++g2) {
    float4v sv[8];
#pragma unroll
    for (int j = 0; j < 8; ++j)
      sv[j] = *(const float4v*)(sp + (size_t)(t0 + g2 * 8 + j) * Nn);

    short8 w0[4], w1[4];                           // per-row (i) 8 bf16 each
#pragma unroll
    for (int j = 0; j < 8; ++j) {
      tr1 *= da; tr2 *= db;                        // decay first
      float4v tv = c1 * tr1 + c2 * (tr1 * tr2);    // trace factor (pre spike-add)
#pragma unroll
      for (int i = 0; i < 4; ++i) {
        unsigned short bs = f2bf(sv[j][i]);
        unsigned short bt = f2bf(tv[i]);
        w0[i][j] = (short)(side ? bs : bt);        // half0: P / post
        w1[i][j] = (short)(side ? bt : bs);        // half1: pre / -Y
      }
      tr1 += sv[j]; tr2 += sv[j];                  // then add spike
    }
    int k0 = t0 + g2 * 8;                          // local t (multiple of 8)
    int kl = b * Tt + k0;                          // global row
    int slot = (k0 >> 3) & 3;                      // 16B slot in this ktile
    size_t tile0 = ((size_t)((kl >> 5) * 8 + (n4 >> 7))) * 4096;
    size_t tile1 = ((size_t)(((Kc + kl) >> 5) * 8 + (n4 >> 7))) * 4096;
#pragma unroll
    for (int i = 0; i < 4; ++i) {
      int n = n4 + i;
      int sw = (n >> 1) & 3;                       // bank swizzle (address only)
      size_t roff = (size_t)(n & 127) * 32 + (size_t)((slot ^ sw) * 8);
      *(short8*)(dbuf + tile0 + roff) = w0[i];
      *(short8*)(dbuf + tile1 + roff) = w1[i];
    }
  }
}

// ---------------------------------------------------------------------------
// Phase 2: wu_partial[s] = A^T * B over this split's k-range.
// 3-stage LDS ring, loads in flight across a bare s_barrier, fine-grained
// s_waitcnt vmcnt (never a full drain). XCD-aware flat grid: s = blockIdx.x&7
// keeps all 64 tile-blocks of a split on one XCD's L2 (R8: FETCH collapse,
// gemm ~<90us). Performance heuristic only; correctness mapping-independent.
// ---------------------------------------------------------------------------
#define GLL(gp, lp)                                                         \
  __builtin_amdgcn_global_load_lds(                                         \
      (const __attribute__((address_space(1))) unsigned int*)(gp),          \
      (__attribute__((address_space(3))) unsigned int*)(lp), 16, 0, 0)

// s_waitcnt imm (gfx9 encoding): lgkm[11:8]=0xF (no wait), exp[6:4]=0x7,
// vmcnt low4 in [3:0], hi2 in [15:14]=0
#define WAITCNT_VM8 0xF78
#define WAITCNT_VM4 0xF74
#define WAITCNT_VM0 0xF70

__global__ __launch_bounds__(BDIM) void gemm_kernel(
    const unsigned short* __restrict__ Abuf, const unsigned short* __restrict__ Bbuf,
    float* __restrict__ partials)
{
  __shared__ unsigned short smem[3 * 8192];  // ring of 3 x (A 8KB-elems | B)
  int tid  = threadIdx.x;
  int s    = blockIdx.x & 7;                 // low bits -> XCD id under round-robin
  int tile = blockIdx.x >> 3;                // [0,64)
  int pt   = tile & 7;
  int qt   = tile >> 3;

  float4v acc[4][4];
#pragma unroll
  for (int i = 0; i < 4; ++i)
#pragma unroll
    for (int j = 0; j < 4; ++j) acc[i][j] = (float4v){0.f, 0.f, 0.f, 0.f};

  int wid = tid >> 6, lane = tid & 63;
  int wr = wid >> 1, wc = wid & 1;
  int rA = wr * 64 + (lane & 15);
  int rB = wc * 64 + (lane & 15);
  // swizzled 16B-slot: lane wants k-group (lane>>4); stored slot is ^((row>>1)&3)
  int kg = (((lane >> 4) ^ ((lane >> 1) & 3)) * 8);

  const unsigned short* ga = Abuf + ((size_t)(s * NKT) * 8 + pt) * 4096 + tid * 8;
  const unsigned short* gb = Bbuf + ((size_t)(s * NKT) * 8 + qt) * 4096 + tid * 8;

  // issue the 4 staging loads for tile kt into ring slot kt%3
#define ISSUE(kt_) do {                                                     \
    unsigned short* sb_ = smem + ((kt_) % 3) * 8192;                        \
    const unsigned short* a_ = ga + (size_t)(kt_) * 8 * 4096;               \
    const unsigned short* b_ = gb + (size_t)(kt_) * 8 * 4096;               \
    GLL(a_,        sb_ + tid * 8);                                          \
    GLL(a_ + 2048, sb_ + 2048 + tid * 8);                                   \
    GLL(b_,        sb_ + 4096 + tid * 8);                                   \
    GLL(b_ + 2048, sb_ + 6144 + tid * 8);                                   \
  } while (0)

  ISSUE(0);
  ISSUE(1);

  for (int kt = 0; kt < NKT; ++kt) {
    if (kt + 2 < NKT) {
      ISSUE(kt + 2);
      __builtin_amdgcn_s_waitcnt(WAITCNT_VM8);   // tile kt landed; kt+1,kt+2 in flight
    } else if (kt + 2 == NKT) {
      __builtin_amdgcn_s_waitcnt(WAITCNT_VM4);   // tile kt landed; kt+1 in flight
    } else {
      __builtin_amdgcn_s_waitcnt(WAITCNT_VM0);   // last tile
    }
    __builtin_amdgcn_s_barrier();                // bare barrier — no vmcnt(0) drain

    const unsigned short* sb = smem + (kt % 3) * 8192;
    short8 af[4], bfv[4];
#pragma unroll
    for (int mi = 0; mi < 4; ++mi)
      af[mi] = *(const short8*)(sb + (rA + mi * 16) * 32 + kg);       // ds_read_b128
#pragma unroll
    for (int ni = 0; ni < 4; ++ni)
      bfv[ni] = *(const short8*)(sb + 4096 + (rB + ni * 16) * 32 + kg);
#pragma unroll
    for (int mi = 0; mi < 4; ++mi)
#pragma unroll
      for (int ni = 0; ni < 4; ++ni)
        acc[mi][ni] = __builtin_amdgcn_mfma_f32_16x16x32_bf16(af[mi], bfv[ni], acc[mi][ni], 0, 0, 0);
  }

  // C/D layout: col = lane&15, row = (lane>>4)*4 + reg.  Single chunk: plain store.
  float* po = partials + (size_t)s * Nn * Nn;
#pragma unroll
  for (int mi = 0; mi < 4; ++mi)
#pragma unroll
    for (int r = 0; r < 4; ++r) {
      int row = pt * 128 + wr * 64 + mi * 16 + (lane >> 4) * 4 + r;
#pragma unroll
      for (int ni = 0; ni < 4; ++ni) {
        int col = qt * 128 + wc * 64 + ni * 16 + (lane & 15);
        po[(size_t)row * Nn + col] = acc[mi][ni][r];
      }
    }
#undef ISSUE
}

// ---------------------------------------------------------------------------
// Phase 3: reduce split-K partials (float4), apply 1/(B*T)
// ---------------------------------------------------------------------------
__global__ __launch_bounds__(BDIM) void reduce_kernel(
    const float4v* __restrict__ partials, float4v* __restrict__ out, int S, float scale)
{
  size_t i = (size_t)blockIdx.x * BDIM + threadIdx.x;
  float4v v = (float4v){0.f, 0.f, 0.f, 0.f};
  for (int s = 0; s < S; ++s) v += partials[(size_t)s * (Nn * Nn / 4) + i];
  out[i] = v * scale;
}

extern "C" void kernel_launch(void* const* d_in, const int* in_sizes, int n_in,
                              void* d_out, int out_size, void* d_ws, size_t ws_size,
                              hipStream_t stream)
{
  const float* pre  = (const float*)d_in[0];
  const float* post = (const float*)d_in[1];
  float4v* out = (float4v*)d_out;
  char* ws = (char*)d_ws;

  size_t sizeAB = (size_t)2 * Bsz * Tt * Nn * 2;   // one operand buffer = 64 MB

  float* partials = (float*)ws;
  unsigned short* Abuf = (unsigned short*)(ws + (size_t)SPLITS * Nn * Nn * 4);
  unsigned short* Bbuf = (unsigned short*)(ws + (size_t)SPLITS * Nn * Nn * 4 + sizeAB);

  float d_plus  = expf(-1.0f / 20.0f);
  float d_x     = expf(-1.0f / 101.0f);
  float d_minus = expf(-1.0f / 20.0f);
  float d_y     = expf(-1.0f / 114.0f);

  trace_kernel<<<2 * Bsz * 16, BDIM, 0, stream>>>(
      pre, post, Abuf, Bbuf, d_plus, d_x, d_minus, d_y);
  gemm_kernel<<<64 * SPLITS, BDIM, 0, stream>>>(Abuf, Bbuf, partials);
  reduce_kernel<<<(Nn * Nn / 4) / BDIM, BDIM, 0, stream>>>(
      (const float4v*)partials, out, SPLITS, 1.0f / (float)(Bsz * Tt));
}